// Round 1
// baseline (871.752 us; speedup 1.0000x reference)
//
#include <hip/hip_runtime.h>
#include <cstdint>

#define NN 16384
#define FF 128
#define RR 16
#define HH 8
#define CC 64
#define HC 512
#define EE 163840
#define ET (EE + NN)   // 180224 edges including self-loops

// ---------------- CSR build (dst-sorted) ----------------
__global__ __launch_bounds__(256) void count_kernel(const int* __restrict__ ei,
                                                    int* __restrict__ counts) {
  int e = blockIdx.x * 256 + threadIdx.x;
  if (e >= ET) return;
  int d = (e < EE) ? ei[EE + e] : (e - EE);
  atomicAdd(&counts[d], 1);
}

__global__ __launch_bounds__(1024) void scan_kernel(const int* __restrict__ counts,
                                                    int* __restrict__ offs,
                                                    int* __restrict__ cursor) {
  __shared__ int part[1024];
  int t = threadIdx.x;
  int base = t * 16;
  int loc[16];
  int s = 0;
#pragma unroll
  for (int i = 0; i < 16; ++i) { loc[i] = s; s += counts[base + i]; }
  part[t] = s;
  __syncthreads();
  for (int off = 1; off < 1024; off <<= 1) {
    int v = (t >= off) ? part[t - off] : 0;
    __syncthreads();
    part[t] += v;
    __syncthreads();
  }
  int excl = part[t] - s;  // exclusive prefix of this thread's chunk
#pragma unroll
  for (int i = 0; i < 16; ++i) {
    int o = excl + loc[i];
    offs[base + i] = o;
    cursor[base + i] = o;
  }
  if (t == 1023) offs[NN] = part[1023];
}

__global__ __launch_bounds__(256) void scatter_kernel(const int* __restrict__ ei,
                                                      int* __restrict__ cursor,
                                                      int* __restrict__ csr) {
  int e = blockIdx.x * 256 + threadIdx.x;
  if (e >= ET) return;
  int d = (e < EE) ? ei[EE + e] : (e - EE);
  int p = atomicAdd(&cursor[d], 1);
  csr[p] = e;
}

// ---------------- fp32 GEMM: C[16384 x 512] = A[16384 x K] @ W[K x 512] + bias ----------------
// 128x128 block tile, 8x8 per thread, BK=16.
__global__ __launch_bounds__(256) void gemm_bias_kernel(const float* __restrict__ A,
                                                        const float* __restrict__ W,
                                                        const float* __restrict__ bias,
                                                        float* __restrict__ C, int K) {
  __shared__ float As[16][128];
  __shared__ float Bs[16][128];
  int tid = threadIdx.x;
  int row0 = blockIdx.y * 128, col0 = blockIdx.x * 128;
  int tx = tid & 15, ty = tid >> 4;
  int lr = tid >> 1, lk = (tid & 1) * 8;   // A tile: 128 rows x 16 k
  int wr = tid >> 4, wc = (tid & 15) * 8;  // W tile: 16 k x 128 cols
  float acc[8][8] = {};
  for (int k0 = 0; k0 < K; k0 += 16) {
    const float* ap = &A[(size_t)(row0 + lr) * K + k0 + lk];
    float4 av0 = *(const float4*)(ap);
    float4 av1 = *(const float4*)(ap + 4);
    const float* wp = &W[(size_t)(k0 + wr) * HC + col0 + wc];
    float4 wv0 = *(const float4*)(wp);
    float4 wv1 = *(const float4*)(wp + 4);
    As[lk + 0][lr] = av0.x; As[lk + 1][lr] = av0.y;
    As[lk + 2][lr] = av0.z; As[lk + 3][lr] = av0.w;
    As[lk + 4][lr] = av1.x; As[lk + 5][lr] = av1.y;
    As[lk + 6][lr] = av1.z; As[lk + 7][lr] = av1.w;
    *(float4*)&Bs[wr][wc] = wv0;
    *(float4*)&Bs[wr][wc + 4] = wv1;
    __syncthreads();
#pragma unroll
    for (int k = 0; k < 16; ++k) {
      float a[8], b[8];
      *(float4*)&a[0] = *(const float4*)&As[k][ty * 8];
      *(float4*)&a[4] = *(const float4*)&As[k][ty * 8 + 4];
      *(float4*)&b[0] = *(const float4*)&Bs[k][tx * 8];
      *(float4*)&b[4] = *(const float4*)&Bs[k][tx * 8 + 4];
#pragma unroll
      for (int i = 0; i < 8; ++i)
#pragma unroll
        for (int j = 0; j < 8; ++j) acc[i][j] += a[i] * b[j];
    }
    __syncthreads();
  }
#pragma unroll
  for (int i = 0; i < 8; ++i) {
    int r = row0 + ty * 8 + i;
    float* cp = &C[(size_t)r * HC + col0 + tx * 8];
    const float* bp = &bias[col0 + tx * 8];
    float4 o0 = make_float4(acc[i][0] + bp[0], acc[i][1] + bp[1],
                            acc[i][2] + bp[2], acc[i][3] + bp[3]);
    float4 o1 = make_float4(acc[i][4] + bp[4], acc[i][5] + bp[5],
                            acc[i][6] + bp[6], acc[i][7] + bp[7]);
    *(float4*)cp = o0;
    *(float4*)(cp + 4) = o1;
  }
}

// ---------------- edge logits: one wave per edge-iteration ----------------
// lane owns channels [lane*8, lane*8+8) of the flattened (H,C)=512; head = lane>>3.
// We fragment (16 x 8 floats) cached in registers -- invariant across edges.
__global__ __launch_bounds__(256) void edge_logits_kernel(const int* __restrict__ ei,
                                                          const float* __restrict__ eattr,
                                                          const float* __restrict__ We,
                                                          const float* __restrict__ att,
                                                          const float* __restrict__ xl,
                                                          const float* __restrict__ xr,
                                                          float* __restrict__ logits) {
  int lane = threadIdx.x & 63;
  int gw = (blockIdx.x * 256 + threadIdx.x) >> 6;  // global wave id
  int nw = gridDim.x * 4;
  int c0 = lane * 8;
  float wf[RR][8];
#pragma unroll
  for (int r = 0; r < RR; ++r) {
    float4 w0 = *(const float4*)&We[r * HC + c0];
    float4 w1 = *(const float4*)&We[r * HC + c0 + 4];
    wf[r][0] = w0.x; wf[r][1] = w0.y; wf[r][2] = w0.z; wf[r][3] = w0.w;
    wf[r][4] = w1.x; wf[r][5] = w1.y; wf[r][6] = w1.z; wf[r][7] = w1.w;
  }
  float am[8];
  {
    float4 a0 = *(const float4*)&att[c0];
    float4 a1 = *(const float4*)&att[c0 + 4];
    am[0] = a0.x; am[1] = a0.y; am[2] = a0.z; am[3] = a0.w;
    am[4] = a1.x; am[5] = a1.y; am[6] = a1.z; am[7] = a1.w;
  }
  int h = lane >> 3;
  for (int e = gw; e < ET; e += nw) {
    int s, d;
    float ev[RR];
    if (e < EE) {
      s = ei[e];
      d = ei[EE + e];
      const float4* ep4 = (const float4*)&eattr[(size_t)e * RR];
      float4 e0 = ep4[0], e1 = ep4[1], e2 = ep4[2], e3 = ep4[3];
      ev[0] = e0.x; ev[1] = e0.y; ev[2] = e0.z; ev[3] = e0.w;
      ev[4] = e1.x; ev[5] = e1.y; ev[6] = e1.z; ev[7] = e1.w;
      ev[8] = e2.x; ev[9] = e2.y; ev[10] = e2.z; ev[11] = e2.w;
      ev[12] = e3.x; ev[13] = e3.y; ev[14] = e3.z; ev[15] = e3.w;
    } else {
      s = d = e - EE;
#pragma unroll
      for (int r = 0; r < RR; ++r) ev[r] = 0.5f;
    }
    float epv[8] = {0.f, 0.f, 0.f, 0.f, 0.f, 0.f, 0.f, 0.f};
#pragma unroll
    for (int r = 0; r < RR; ++r)
#pragma unroll
      for (int j = 0; j < 8; ++j) epv[j] += ev[r] * wf[r][j];
    const float* pl = &xl[(size_t)s * HC + c0];
    const float* pr = &xr[(size_t)d * HC + c0];
    float4 l0 = *(const float4*)pl, l1 = *(const float4*)(pl + 4);
    float4 r0 = *(const float4*)pr, r1 = *(const float4*)(pr + 4);
    float zl[8] = {l0.x + r0.x, l0.y + r0.y, l0.z + r0.z, l0.w + r0.w,
                   l1.x + r1.x, l1.y + r1.y, l1.z + r1.z, l1.w + r1.w};
    float sum = 0.f;
#pragma unroll
    for (int j = 0; j < 8; ++j) {
      float zz = zl[j] + epv[j];
      zz = (zz > 0.f) ? zz : 0.2f * zz;
      sum += zz * am[j];
    }
    sum += __shfl_xor(sum, 1);
    sum += __shfl_xor(sum, 2);
    sum += __shfl_xor(sum, 4);
    if ((lane & 7) == 0) logits[(size_t)e * 8 + h] = sum;
  }
}

// ---------------- per-node segment softmax (in-place logits -> alpha) ----------------
// one wave per node; lane = (edge-slot i0 = lane>>3, head h = lane&7)
__global__ __launch_bounds__(256) void softmax_kernel(const int* __restrict__ offs,
                                                      const int* __restrict__ csr,
                                                      float* __restrict__ logits) {
  int lane = threadIdx.x & 63;
  int n = blockIdx.x * 4 + (threadIdx.x >> 6);
  int h = lane & 7, i0 = lane >> 3;
  int beg = offs[n], end = offs[n + 1];
  float m = -1e30f;
  for (int i = beg + i0; i < end; i += 8) m = fmaxf(m, logits[(size_t)csr[i] * 8 + h]);
  m = fmaxf(m, __shfl_xor(m, 8));
  m = fmaxf(m, __shfl_xor(m, 16));
  m = fmaxf(m, __shfl_xor(m, 32));
  float s = 0.f;
  for (int i = beg + i0; i < end; i += 8) s += __expf(logits[(size_t)csr[i] * 8 + h] - m);
  s += __shfl_xor(s, 8);
  s += __shfl_xor(s, 16);
  s += __shfl_xor(s, 32);
  float inv = 1.f / (s + 1e-16f);
  for (int i = beg + i0; i < end; i += 8) {
    size_t idx = (size_t)csr[i] * 8 + h;
    logits[idx] = __expf(logits[idx] - m) * inv;
  }
}

// ---------------- aggregation: out[n] = sum_e alpha_e * xl[src_e] (+bias), concat ----------------
__global__ __launch_bounds__(256) void aggregate_concat_kernel(const int* __restrict__ ei,
                                                               const int* __restrict__ offs,
                                                               const int* __restrict__ csr,
                                                               const float* __restrict__ alpha,
                                                               const float* __restrict__ xl,
                                                               const float* __restrict__ bias,
                                                               float* __restrict__ out) {
  int n = blockIdx.x, t = threadIdx.x;
  int beg = offs[n], end = offs[n + 1];
  int c0 = t, c1 = t + 256;
  int h0 = c0 >> 6, h1 = c1 >> 6;
  float acc0 = 0.f, acc1 = 0.f;
  for (int i = beg; i < end; ++i) {
    int e = csr[i];
    int s = (e < EE) ? ei[e] : (e - EE);
    float a0 = alpha[(size_t)e * 8 + h0];
    float a1 = alpha[(size_t)e * 8 + h1];
    acc0 += a0 * xl[(size_t)s * HC + c0];
    acc1 += a1 * xl[(size_t)s * HC + c1];
  }
  out[(size_t)n * HC + c0] = acc0 + bias[c0];
  out[(size_t)n * HC + c1] = acc1 + bias[c1];
}

// ---------------- aggregation with mean over heads (+bias2), layer-2 epilogue ----------------
__global__ __launch_bounds__(256) void aggregate_mean_kernel(const int* __restrict__ ei,
                                                             const int* __restrict__ offs,
                                                             const int* __restrict__ csr,
                                                             const float* __restrict__ alpha,
                                                             const float* __restrict__ xl,
                                                             const float* __restrict__ bias2,
                                                             float* __restrict__ out) {
  __shared__ float red[HC];
  int n = blockIdx.x, t = threadIdx.x;
  int beg = offs[n], end = offs[n + 1];
  int c0 = t, c1 = t + 256;
  int h0 = c0 >> 6, h1 = c1 >> 6;
  float acc0 = 0.f, acc1 = 0.f;
  for (int i = beg; i < end; ++i) {
    int e = csr[i];
    int s = (e < EE) ? ei[e] : (e - EE);
    float a0 = alpha[(size_t)e * 8 + h0];
    float a1 = alpha[(size_t)e * 8 + h1];
    acc0 += a0 * xl[(size_t)s * HC + c0];
    acc1 += a1 * xl[(size_t)s * HC + c1];
  }
  red[c0] = acc0;
  red[c1] = acc1;
  __syncthreads();
  if (t < CC) {
    float ssum = 0.f;
#pragma unroll
    for (int hh = 0; hh < HH; ++hh) ssum += red[hh * CC + t];
    out[(size_t)n * CC + t] = ssum * 0.125f + bias2[t];
  }
}

extern "C" void kernel_launch(void* const* d_in, const int* in_sizes, int n_in,
                              void* d_out, int out_size, void* d_ws, size_t ws_size,
                              hipStream_t stream) {
  const float* x     = (const float*)d_in[0];
  const int*   ei    = (const int*)d_in[1];
  const float* eattr = (const float*)d_in[2];
  const float* Wl1   = (const float*)d_in[3];
  const float* bl1   = (const float*)d_in[4];
  const float* Wr1   = (const float*)d_in[5];
  const float* br1   = (const float*)d_in[6];
  const float* We1   = (const float*)d_in[7];
  const float* att1  = (const float*)d_in[8];
  const float* bias1 = (const float*)d_in[9];
  const float* Wl2   = (const float*)d_in[10];
  const float* bl2   = (const float*)d_in[11];
  const float* Wr2   = (const float*)d_in[12];
  const float* br2   = (const float*)d_in[13];
  const float* We2   = (const float*)d_in[14];
  const float* att2  = (const float*)d_in[15];
  const float* bias2 = (const float*)d_in[16];
  float* out = (float*)d_out;

  char* ws = (char*)d_ws;
  size_t off = 0;
  auto alloc = [&](size_t bytes) {
    char* p = ws + off;
    off += (bytes + 255) & ~(size_t)255;
    return p;
  };
  float* bufA   = (float*)alloc((size_t)NN * HC * 4);  // xl (layer 1 then layer 2)
  float* bufB   = (float*)alloc((size_t)NN * HC * 4);  // xr
  float* bufO   = (float*)alloc((size_t)NN * HC * 4);  // layer-1 output
  float* logits = (float*)alloc((size_t)ET * HH * 4);  // logits -> alpha in place
  int* counts = (int*)alloc((size_t)NN * 4);
  int* offs   = (int*)alloc((size_t)(NN + 1) * 4);
  int* cursor = (int*)alloc((size_t)NN * 4);
  int* csr    = (int*)alloc((size_t)ET * 4);
  (void)ws_size; (void)in_sizes; (void)n_in; (void)out_size;

  // CSR build (must redo every launch; ws is re-poisoned)
  hipMemsetAsync(counts, 0, (size_t)NN * 4, stream);
  int eb = (ET + 255) / 256;
  count_kernel<<<eb, 256, 0, stream>>>(ei, counts);
  scan_kernel<<<1, 1024, 0, stream>>>(counts, offs, cursor);
  scatter_kernel<<<eb, 256, 0, stream>>>(ei, cursor, csr);

  dim3 ggrid(HC / 128, NN / 128);

  // ---- layer 1 ----
  gemm_bias_kernel<<<ggrid, 256, 0, stream>>>(x, Wl1, bl1, bufA, FF);
  gemm_bias_kernel<<<ggrid, 256, 0, stream>>>(x, Wr1, br1, bufB, FF);
  edge_logits_kernel<<<4096, 256, 0, stream>>>(ei, eattr, We1, att1, bufA, bufB, logits);
  softmax_kernel<<<NN / 4, 256, 0, stream>>>(offs, csr, logits);
  aggregate_concat_kernel<<<NN, 256, 0, stream>>>(ei, offs, csr, logits, bufA, bias1, bufO);

  // ---- layer 2 ----
  gemm_bias_kernel<<<ggrid, 256, 0, stream>>>(bufO, Wl2, bl2, bufA, HC);
  gemm_bias_kernel<<<ggrid, 256, 0, stream>>>(bufO, Wr2, br2, bufB, HC);
  edge_logits_kernel<<<4096, 256, 0, stream>>>(ei, eattr, We2, att2, bufA, bufB, logits);
  softmax_kernel<<<NN / 4, 256, 0, stream>>>(offs, csr, logits);
  aggregate_mean_kernel<<<NN, 256, 0, stream>>>(ei, offs, csr, logits, bufA, bias2, out);
}

// Round 2
// 744.400 us; speedup vs baseline: 1.1711x; 1.1711x over previous
//
#include <hip/hip_runtime.h>
#include <cstdint>

#define NN 16384
#define FF 128
#define RR 16
#define HH 8
#define CC 64
#define HC 512
#define EE 163840
#define ET (EE + NN)   // 180224 edges including self-loops (64-divisible)

// ---------------- CSR build (dst-sorted) ----------------
__global__ __launch_bounds__(256) void count_kernel(const int* __restrict__ ei,
                                                    int* __restrict__ counts) {
  int e = blockIdx.x * 256 + threadIdx.x;
  if (e >= ET) return;
  int d = (e < EE) ? ei[EE + e] : (e - EE);
  atomicAdd(&counts[d], 1);
}

__global__ __launch_bounds__(1024) void scan_kernel(const int* __restrict__ counts,
                                                    int* __restrict__ offs,
                                                    int* __restrict__ cursor) {
  __shared__ int part[1024];
  int t = threadIdx.x;
  int base = t * 16;
  int loc[16];
  int s = 0;
#pragma unroll
  for (int i = 0; i < 16; ++i) { loc[i] = s; s += counts[base + i]; }
  part[t] = s;
  __syncthreads();
  for (int off = 1; off < 1024; off <<= 1) {
    int v = (t >= off) ? part[t - off] : 0;
    __syncthreads();
    part[t] += v;
    __syncthreads();
  }
  int excl = part[t] - s;  // exclusive prefix of this thread's chunk
#pragma unroll
  for (int i = 0; i < 16; ++i) {
    int o = excl + loc[i];
    offs[base + i] = o;
    cursor[base + i] = o;
  }
  if (t == 1023) offs[NN] = part[1023];
}

__global__ __launch_bounds__(256) void scatter_kernel(const int* __restrict__ ei,
                                                      int* __restrict__ cursor,
                                                      int* __restrict__ csr,
                                                      int* __restrict__ srcc,
                                                      int* __restrict__ dstc) {
  int e = blockIdx.x * 256 + threadIdx.x;
  if (e >= ET) return;
  int s, d;
  if (e < EE) { s = ei[e]; d = ei[EE + e]; }
  else        { s = d = e - EE; }
  int p = atomicAdd(&cursor[d], 1);
  csr[p] = e;
  srcc[p] = s;
  dstc[p] = d;
}

// ---------------- fp32 GEMM: C[16384 x 512] = A[16384 x K] @ W[K x 512] + bias ----------------
// 128x128 block tile, 8x8 per thread, BK=16.
__global__ __launch_bounds__(256) void gemm_bias_kernel(const float* __restrict__ A,
                                                        const float* __restrict__ W,
                                                        const float* __restrict__ bias,
                                                        float* __restrict__ C, int K) {
  __shared__ float As[16][128];
  __shared__ float Bs[16][128];
  int tid = threadIdx.x;
  int row0 = blockIdx.y * 128, col0 = blockIdx.x * 128;
  int tx = tid & 15, ty = tid >> 4;
  int lr = tid >> 1, lk = (tid & 1) * 8;   // A tile: 128 rows x 16 k
  int wr = tid >> 4, wc = (tid & 15) * 8;  // W tile: 16 k x 128 cols
  float acc[8][8] = {};
  for (int k0 = 0; k0 < K; k0 += 16) {
    const float* ap = &A[(size_t)(row0 + lr) * K + k0 + lk];
    float4 av0 = *(const float4*)(ap);
    float4 av1 = *(const float4*)(ap + 4);
    const float* wp = &W[(size_t)(k0 + wr) * HC + col0 + wc];
    float4 wv0 = *(const float4*)(wp);
    float4 wv1 = *(const float4*)(wp + 4);
    As[lk + 0][lr] = av0.x; As[lk + 1][lr] = av0.y;
    As[lk + 2][lr] = av0.z; As[lk + 3][lr] = av0.w;
    As[lk + 4][lr] = av1.x; As[lk + 5][lr] = av1.y;
    As[lk + 6][lr] = av1.z; As[lk + 7][lr] = av1.w;
    *(float4*)&Bs[wr][wc] = wv0;
    *(float4*)&Bs[wr][wc + 4] = wv1;
    __syncthreads();
#pragma unroll
    for (int k = 0; k < 16; ++k) {
      float a[8], b[8];
      *(float4*)&a[0] = *(const float4*)&As[k][ty * 8];
      *(float4*)&a[4] = *(const float4*)&As[k][ty * 8 + 4];
      *(float4*)&b[0] = *(const float4*)&Bs[k][tx * 8];
      *(float4*)&b[4] = *(const float4*)&Bs[k][tx * 8 + 4];
#pragma unroll
      for (int i = 0; i < 8; ++i)
#pragma unroll
        for (int j = 0; j < 8; ++j) acc[i][j] += a[i] * b[j];
    }
    __syncthreads();
  }
#pragma unroll
  for (int i = 0; i < 8; ++i) {
    int r = row0 + ty * 8 + i;
    float* cp = &C[(size_t)r * HC + col0 + tx * 8];
    const float* bp = &bias[col0 + tx * 8];
    float4 o0 = make_float4(acc[i][0] + bp[0], acc[i][1] + bp[1],
                            acc[i][2] + bp[2], acc[i][3] + bp[3]);
    float4 o1 = make_float4(acc[i][4] + bp[4], acc[i][5] + bp[5],
                            acc[i][6] + bp[6], acc[i][7] + bp[7]);
    *(float4*)cp = o0;
    *(float4*)(cp + 4) = o1;
  }
}

// ---------------- edge logits: one block per 64 CSR slots ----------------
// thread owns 2 channels (c0 = 2*tid); We fragment = 16x2 = 32 VGPRs (no spill).
// Edge attrs + src/dst staged in LDS per batch. Logits written CSR-ordered.
__global__ __launch_bounds__(256) void edge_logits_kernel(const int* __restrict__ csr,
                                                          const int* __restrict__ srcc,
                                                          const int* __restrict__ dstc,
                                                          const float* __restrict__ eattr,
                                                          const float* __restrict__ We,
                                                          const float* __restrict__ att,
                                                          const float* __restrict__ xl,
                                                          const float* __restrict__ xr,
                                                          float* __restrict__ logitsc) {
  __shared__ float se[64][16];
  __shared__ int ssrc[64];
  __shared__ int sdst[64];
  __shared__ int sedge[64];
  int t = threadIdx.x;
  int base = blockIdx.x * 64;
  int c0 = t * 2;
  float wf[RR][2];
#pragma unroll
  for (int r = 0; r < RR; ++r) {
    float2 w = *(const float2*)&We[r * HC + c0];
    wf[r][0] = w.x; wf[r][1] = w.y;
  }
  float2 amv = *(const float2*)&att[c0];
  if (t < 64) {
    int i = base + t;
    sedge[t] = csr[i];
    ssrc[t] = srcc[i];
    sdst[t] = dstc[i];
  }
  __syncthreads();
  {
    int k = t >> 2, r0 = (t & 3) * 4;
    int e = sedge[k];
    float4 v;
    if (e < EE) v = *(const float4*)&eattr[(size_t)e * RR + r0];
    else        v = make_float4(0.5f, 0.5f, 0.5f, 0.5f);
    se[k][r0 + 0] = v.x; se[k][r0 + 1] = v.y;
    se[k][r0 + 2] = v.z; se[k][r0 + 3] = v.w;
  }
  __syncthreads();
  int h = t >> 5;  // head of this thread's 2 channels
#pragma unroll 2
  for (int k = 0; k < 64; ++k) {
    int s = ssrc[k], d = sdst[k];
    float2 lv = *(const float2*)&xl[(size_t)s * HC + c0];
    float2 rv = *(const float2*)&xr[(size_t)d * HC + c0];
    const float4* sk = (const float4*)se[k];
    float4 e0 = sk[0], e1 = sk[1], e2 = sk[2], e3 = sk[3];
    float er[RR] = {e0.x, e0.y, e0.z, e0.w, e1.x, e1.y, e1.z, e1.w,
                    e2.x, e2.y, e2.z, e2.w, e3.x, e3.y, e3.z, e3.w};
    float ep0 = 0.f, ep1 = 0.f;
#pragma unroll
    for (int r = 0; r < RR; ++r) { ep0 += er[r] * wf[r][0]; ep1 += er[r] * wf[r][1]; }
    float z0 = lv.x + rv.x + ep0;
    float z1 = lv.y + rv.y + ep1;
    z0 = (z0 > 0.f) ? z0 : 0.2f * z0;
    z1 = (z1 > 0.f) ? z1 : 0.2f * z1;
    float p = z0 * amv.x + z1 * amv.y;
    p += __shfl_xor(p, 1);
    p += __shfl_xor(p, 2);
    p += __shfl_xor(p, 4);
    p += __shfl_xor(p, 8);
    p += __shfl_xor(p, 16);
    if ((t & 31) == 0) logitsc[(size_t)(base + k) * 8 + h] = p;
  }
}

// ---------------- per-node segment softmax (CSR-contiguous, in-place) ----------------
// one wave per node; lane = (edge-slot i0 = lane>>3, head h = lane&7)
__global__ __launch_bounds__(256) void softmax_kernel(const int* __restrict__ offs,
                                                      float* __restrict__ logitsc) {
  int lane = threadIdx.x & 63;
  int n = blockIdx.x * 4 + (threadIdx.x >> 6);
  int h = lane & 7, i0 = lane >> 3;
  int beg = offs[n], end = offs[n + 1];
  float m = -1e30f;
  for (int i = beg + i0; i < end; i += 8) m = fmaxf(m, logitsc[(size_t)i * 8 + h]);
  m = fmaxf(m, __shfl_xor(m, 8));
  m = fmaxf(m, __shfl_xor(m, 16));
  m = fmaxf(m, __shfl_xor(m, 32));
  float s = 0.f;
  for (int i = beg + i0; i < end; i += 8) {
    size_t idx = (size_t)i * 8 + h;
    float v = __expf(logitsc[idx] - m);
    logitsc[idx] = v;
    s += v;
  }
  s += __shfl_xor(s, 8);
  s += __shfl_xor(s, 16);
  s += __shfl_xor(s, 32);
  float inv = 1.f / (s + 1e-16f);
  for (int i = beg + i0; i < end; i += 8) {
    size_t idx = (size_t)i * 8 + h;
    logitsc[idx] *= inv;
  }
}

// ---------------- aggregation: out[n] = sum_i alpha_i * xl[srcc_i] (+bias), concat ----------------
__global__ __launch_bounds__(256) void aggregate_concat_kernel(const int* __restrict__ srcc,
                                                               const int* __restrict__ offs,
                                                               const float* __restrict__ alphac,
                                                               const float* __restrict__ xl,
                                                               const float* __restrict__ bias,
                                                               float* __restrict__ out) {
  int n = blockIdx.x, t = threadIdx.x;
  int beg = offs[n], end = offs[n + 1];
  int c0 = t, c1 = t + 256;
  int h0 = t >> 6, h1 = h0 + 4;
  float acc0 = 0.f, acc1 = 0.f;
#pragma unroll 2
  for (int i = beg; i < end; ++i) {
    int s = srcc[i];
    float a0 = alphac[(size_t)i * 8 + h0];
    float a1 = alphac[(size_t)i * 8 + h1];
    acc0 += a0 * xl[(size_t)s * HC + c0];
    acc1 += a1 * xl[(size_t)s * HC + c1];
  }
  out[(size_t)n * HC + c0] = acc0 + bias[c0];
  out[(size_t)n * HC + c1] = acc1 + bias[c1];
}

// ---------------- aggregation with mean over heads (+bias2), layer-2 epilogue ----------------
__global__ __launch_bounds__(256) void aggregate_mean_kernel(const int* __restrict__ srcc,
                                                             const int* __restrict__ offs,
                                                             const float* __restrict__ alphac,
                                                             const float* __restrict__ xl,
                                                             const float* __restrict__ bias2,
                                                             float* __restrict__ out) {
  __shared__ float red[HC];
  int n = blockIdx.x, t = threadIdx.x;
  int beg = offs[n], end = offs[n + 1];
  int c0 = t, c1 = t + 256;
  int h0 = t >> 6, h1 = h0 + 4;
  float acc0 = 0.f, acc1 = 0.f;
#pragma unroll 2
  for (int i = beg; i < end; ++i) {
    int s = srcc[i];
    float a0 = alphac[(size_t)i * 8 + h0];
    float a1 = alphac[(size_t)i * 8 + h1];
    acc0 += a0 * xl[(size_t)s * HC + c0];
    acc1 += a1 * xl[(size_t)s * HC + c1];
  }
  red[c0] = acc0;
  red[c1] = acc1;
  __syncthreads();
  if (t < CC) {
    float ssum = 0.f;
#pragma unroll
    for (int hh = 0; hh < HH; ++hh) ssum += red[hh * CC + t];
    out[(size_t)n * CC + t] = ssum * 0.125f + bias2[t];
  }
}

extern "C" void kernel_launch(void* const* d_in, const int* in_sizes, int n_in,
                              void* d_out, int out_size, void* d_ws, size_t ws_size,
                              hipStream_t stream) {
  const float* x     = (const float*)d_in[0];
  const int*   ei    = (const int*)d_in[1];
  const float* eattr = (const float*)d_in[2];
  const float* Wl1   = (const float*)d_in[3];
  const float* bl1   = (const float*)d_in[4];
  const float* Wr1   = (const float*)d_in[5];
  const float* br1   = (const float*)d_in[6];
  const float* We1   = (const float*)d_in[7];
  const float* att1  = (const float*)d_in[8];
  const float* bias1 = (const float*)d_in[9];
  const float* Wl2   = (const float*)d_in[10];
  const float* bl2   = (const float*)d_in[11];
  const float* Wr2   = (const float*)d_in[12];
  const float* br2   = (const float*)d_in[13];
  const float* We2   = (const float*)d_in[14];
  const float* att2  = (const float*)d_in[15];
  const float* bias2 = (const float*)d_in[16];
  float* out = (float*)d_out;

  char* ws = (char*)d_ws;
  size_t off = 0;
  auto alloc = [&](size_t bytes) {
    char* p = ws + off;
    off += (bytes + 255) & ~(size_t)255;
    return p;
  };
  float* bufA   = (float*)alloc((size_t)NN * HC * 4);  // xl (layer 1 then layer 2)
  float* bufB   = (float*)alloc((size_t)NN * HC * 4);  // xr
  float* bufO   = (float*)alloc((size_t)NN * HC * 4);  // layer-1 output
  float* logits = (float*)alloc((size_t)ET * HH * 4);  // logits -> alpha in place (CSR order)
  int* counts = (int*)alloc((size_t)NN * 4);
  int* offs   = (int*)alloc((size_t)(NN + 1) * 4);
  int* cursor = (int*)alloc((size_t)NN * 4);
  int* csr    = (int*)alloc((size_t)ET * 4);
  int* srcc   = (int*)alloc((size_t)ET * 4);
  int* dstc   = (int*)alloc((size_t)ET * 4);
  (void)ws_size; (void)in_sizes; (void)n_in; (void)out_size;

  // CSR build (must redo every launch; ws is re-poisoned)
  hipMemsetAsync(counts, 0, (size_t)NN * 4, stream);
  int eb = (ET + 255) / 256;
  count_kernel<<<eb, 256, 0, stream>>>(ei, counts);
  scan_kernel<<<1, 1024, 0, stream>>>(counts, offs, cursor);
  scatter_kernel<<<eb, 256, 0, stream>>>(ei, cursor, csr, srcc, dstc);

  dim3 ggrid(HC / 128, NN / 128);
  int elb = ET / 64;  // 2816 blocks

  // ---- layer 1 ----
  gemm_bias_kernel<<<ggrid, 256, 0, stream>>>(x, Wl1, bl1, bufA, FF);
  gemm_bias_kernel<<<ggrid, 256, 0, stream>>>(x, Wr1, br1, bufB, FF);
  edge_logits_kernel<<<elb, 256, 0, stream>>>(csr, srcc, dstc, eattr, We1, att1, bufA, bufB, logits);
  softmax_kernel<<<NN / 4, 256, 0, stream>>>(offs, logits);
  aggregate_concat_kernel<<<NN, 256, 0, stream>>>(srcc, offs, logits, bufA, bias1, bufO);

  // ---- layer 2 ----
  gemm_bias_kernel<<<ggrid, 256, 0, stream>>>(bufO, Wl2, bl2, bufA, HC);
  gemm_bias_kernel<<<ggrid, 256, 0, stream>>>(bufO, Wr2, br2, bufB, HC);
  edge_logits_kernel<<<elb, 256, 0, stream>>>(csr, srcc, dstc, eattr, We2, att2, bufA, bufB, logits);
  softmax_kernel<<<NN / 4, 256, 0, stream>>>(offs, logits);
  aggregate_mean_kernel<<<NN, 256, 0, stream>>>(srcc, offs, logits, bufA, bias2, out);
}

// Round 3
// 552.747 us; speedup vs baseline: 1.5771x; 1.3467x over previous
//
#include <hip/hip_runtime.h>
#include <cstdint>

#define NN 16384
#define FF 128
#define RR 16
#define HH 8
#define CC 64
#define HC 512
#define NC 1024          // fused Wl|Wr output width
#define EE 163840
#define ET (EE + NN)     // 180224 edges including self-loops (64-divisible)

typedef __attribute__((ext_vector_type(4))) float f32x4;
typedef __attribute__((ext_vector_type(8))) short short8;

__device__ __forceinline__ unsigned short f2bf(float f) {
  unsigned u = __builtin_bit_cast(unsigned, f);
  u = (u + 0x7FFFu + ((u >> 16) & 1u)) >> 16;   // RNE
  return (unsigned short)u;
}
__device__ __forceinline__ float bf2f(unsigned short b) {
  unsigned u = ((unsigned)b) << 16;
  return __builtin_bit_cast(float, u);
}

__device__ __forceinline__ void gl_lds16(const void* g, void* l) {
  __builtin_amdgcn_global_load_lds(
      (const __attribute__((address_space(1))) unsigned int*)g,
      (__attribute__((address_space(3))) unsigned int*)l, 16, 0, 0);
}

// ---------------- CSR build (dst-sorted) ----------------
__global__ __launch_bounds__(256) void count_kernel(const int* __restrict__ ei,
                                                    int* __restrict__ counts) {
  int e = blockIdx.x * 256 + threadIdx.x;
  if (e >= ET) return;
  int d = (e < EE) ? ei[EE + e] : (e - EE);
  atomicAdd(&counts[d], 1);
}

__global__ __launch_bounds__(1024) void scan_kernel(const int* __restrict__ counts,
                                                    int* __restrict__ offs,
                                                    int* __restrict__ cursor) {
  __shared__ int part[1024];
  int t = threadIdx.x;
  int base = t * 16;
  int loc[16];
  int s = 0;
#pragma unroll
  for (int i = 0; i < 16; ++i) { loc[i] = s; s += counts[base + i]; }
  part[t] = s;
  __syncthreads();
  for (int off = 1; off < 1024; off <<= 1) {
    int v = (t >= off) ? part[t - off] : 0;
    __syncthreads();
    part[t] += v;
    __syncthreads();
  }
  int excl = part[t] - s;
#pragma unroll
  for (int i = 0; i < 16; ++i) {
    int o = excl + loc[i];
    offs[base + i] = o;
    cursor[base + i] = o;
  }
  if (t == 1023) offs[NN] = part[1023];
}

__global__ __launch_bounds__(256) void scatter_kernel(const int* __restrict__ ei,
                                                      int* __restrict__ cursor,
                                                      int* __restrict__ csr,
                                                      int* __restrict__ srcc,
                                                      int* __restrict__ dstc) {
  int e = blockIdx.x * 256 + threadIdx.x;
  if (e >= ET) return;
  int s, d;
  if (e < EE) { s = ei[e]; d = ei[EE + e]; }
  else        { s = d = e - EE; }
  int p = atomicAdd(&cursor[d], 1);
  csr[p] = e;
  srcc[p] = s;
  dstc[p] = d;
}

// ---------------- packing: fp32 -> split bf16 (hi/lo), k-chunk-tiled + swizzled ----------------
// A packed layout: [rb = M/128][kb = K/32][r = 128][k' = 32] where the four 8-elem
// chunks of each row are stored at slot chs = (ch + (r>>1)) & 3 (bank swizzle).
__global__ __launch_bounds__(256) void pack_a_kernel(const float* __restrict__ A,
                                                     unsigned short* __restrict__ Ah,
                                                     unsigned short* __restrict__ Al,
                                                     int K) {
  int nkb = K >> 5;
  int rb = blockIdx.x / nkb, kb = blockIdx.x % nkb;
  int t = threadIdx.x;
  size_t obase = ((size_t)rb * nkb + kb) * 4096;
#pragma unroll
  for (int u = 0; u < 2; ++u) {
    int lin = t + u * 256;          // r*4 + ch
    int r = lin >> 2, ch = lin & 3;
    int chs = (ch + (r >> 1)) & 3;
    const float* src = &A[(size_t)(rb * 128 + r) * K + kb * 32 + ch * 8];
    float4 v0 = *(const float4*)src;
    float4 v1 = *(const float4*)(src + 4);
    float v[8] = {v0.x, v0.y, v0.z, v0.w, v1.x, v1.y, v1.z, v1.w};
    short8 hv, lv;
#pragma unroll
    for (int j = 0; j < 8; ++j) {
      unsigned short h = f2bf(v[j]);
      unsigned short l = f2bf(v[j] - bf2f(h));
      hv[j] = (short)h; lv[j] = (short)l;
    }
    size_t o = obase + (size_t)r * 32 + chs * 8;
    *(short8*)&Ah[o] = hv;
    *(short8*)&Al[o] = lv;
  }
}

// W packed (B operand, [n][k] within tile): [nb = NC/128][kb][n = 128][k' = 32],
// chunk swizzle keyed by n. Sources: n<512 -> Wl[k][n], else Wr[k][n-512].
__global__ __launch_bounds__(256) void pack_w_kernel(const float* __restrict__ Wl,
                                                     const float* __restrict__ Wr,
                                                     unsigned short* __restrict__ Bh,
                                                     unsigned short* __restrict__ Bl,
                                                     int K) {
  int nkb = K >> 5;
  int nb = blockIdx.x / nkb, kb = blockIdx.x % nkb;
  int t = threadIdx.x;
  size_t obase = ((size_t)nb * nkb + kb) * 4096;
#pragma unroll
  for (int u = 0; u < 2; ++u) {
    int lin = t + u * 256;          // n*4 + ch
    int n = lin >> 2, ch = lin & 3;
    int chs = (ch + (n >> 1)) & 3;
    int gn = nb * 128 + n;
    const float* W = (gn < HC) ? Wl : Wr;
    int cn = gn & (HC - 1);
    short8 hv, lv;
#pragma unroll
    for (int j = 0; j < 8; ++j) {
      float f = W[(size_t)(kb * 32 + ch * 8 + j) * HC + cn];
      unsigned short h = f2bf(f);
      unsigned short l = f2bf(f - bf2f(h));
      hv[j] = (short)h; lv[j] = (short)l;
    }
    size_t o = obase + (size_t)n * 32 + chs * 8;
    *(short8*)&Bh[o] = hv;
    *(short8*)&Bl[o] = lv;
  }
}

// ---------------- split-bf16 MFMA GEMM: C[M x 1024] = A[M x K] @ [Wl|Wr] + [bl|br] ----------------
// 128x128 tile, 4 waves (2x2 of 64x64), 16x16x32 bf16 MFMA, 3-product split.
__global__ __launch_bounds__(256) void gemm_mfma_kernel(const unsigned short* __restrict__ Ah,
                                                        const unsigned short* __restrict__ Al,
                                                        const unsigned short* __restrict__ Bh,
                                                        const unsigned short* __restrict__ Bl,
                                                        const float* __restrict__ bl,
                                                        const float* __restrict__ br,
                                                        float* __restrict__ C, int K) {
  __shared__ unsigned short lAh[4096], lAl[4096], lBh[4096], lBl[4096];
  int tid = threadIdx.x;
  int wave = tid >> 6, lane = tid & 63;
  int l15 = lane & 15, quad = lane >> 4;
  int wm = wave >> 1, wn = wave & 1;
  int nb = blockIdx.x, rb = blockIdx.y;
  int nkb = K >> 5;

  const unsigned short* src = (wave == 0) ? Ah : (wave == 1) ? Al : (wave == 2) ? Bh : Bl;
  unsigned short* dst = (wave == 0) ? lAh : (wave == 1) ? lAl : (wave == 2) ? lBh : lBl;
  int blk = (wave < 2) ? rb : nb;
  size_t gstep = 4096;
  const unsigned short* gbase = src + ((size_t)blk * nkb) * gstep + lane * 8;

  f32x4 acc[4][4];
#pragma unroll
  for (int i = 0; i < 4; ++i)
#pragma unroll
    for (int j = 0; j < 4; ++j) acc[i][j] = (f32x4){0.f, 0.f, 0.f, 0.f};

  // fragment LDS offsets (elements)
  int offA[4], offB[4];
#pragma unroll
  for (int t = 0; t < 4; ++t) {
    int ra = wm * 64 + t * 16 + l15;
    offA[t] = ra * 32 + ((quad + (ra >> 1)) & 3) * 8;
    int rbn = wn * 64 + t * 16 + l15;
    offB[t] = rbn * 32 + ((quad + (rbn >> 1)) & 3) * 8;
  }

  for (int kb = 0; kb < nkb; ++kb) {
    const unsigned short* g = gbase + (size_t)kb * gstep;
#pragma unroll
    for (int i = 0; i < 8; ++i)
      gl_lds16(g + i * 512, dst + i * 512);
    __syncthreads();

    short8 ah[4], al_[4], bh[4], bl_[4];
#pragma unroll
    for (int t = 0; t < 4; ++t) {
      ah[t]  = *(const short8*)&lAh[offA[t]];
      al_[t] = *(const short8*)&lAl[offA[t]];
      bh[t]  = *(const short8*)&lBh[offB[t]];
      bl_[t] = *(const short8*)&lBl[offB[t]];
    }
#pragma unroll
    for (int tm = 0; tm < 4; ++tm)
#pragma unroll
      for (int tn = 0; tn < 4; ++tn) {
        acc[tm][tn] = __builtin_amdgcn_mfma_f32_16x16x32_bf16(ah[tm], bh[tn], acc[tm][tn], 0, 0, 0);
        acc[tm][tn] = __builtin_amdgcn_mfma_f32_16x16x32_bf16(ah[tm], bl_[tn], acc[tm][tn], 0, 0, 0);
        acc[tm][tn] = __builtin_amdgcn_mfma_f32_16x16x32_bf16(al_[tm], bh[tn], acc[tm][tn], 0, 0, 0);
      }
    __syncthreads();
  }

  // epilogue: C/D layout col = lane&15, row = quad*4 + reg
#pragma unroll
  for (int tm = 0; tm < 4; ++tm) {
    int row = rb * 128 + wm * 64 + tm * 16 + quad * 4;
#pragma unroll
    for (int tn = 0; tn < 4; ++tn) {
      int col = nb * 128 + wn * 64 + tn * 16 + l15;
      float bias = (col < HC) ? bl[col] : br[col - HC];
#pragma unroll
      for (int r = 0; r < 4; ++r)
        C[(size_t)(row + r) * NC + col] = acc[tm][tn][r] + bias;
    }
  }
}

// ---------------- edge logits: one block per 64 CSR slots ----------------
// xlr = fused GEMM output [N x 1024]: xl = cols 0..511, xr = cols 512..1023.
__global__ __launch_bounds__(256) void edge_logits_kernel(const int* __restrict__ csr,
                                                          const int* __restrict__ srcc,
                                                          const int* __restrict__ dstc,
                                                          const float* __restrict__ eattr,
                                                          const float* __restrict__ We,
                                                          const float* __restrict__ att,
                                                          const float* __restrict__ xlr,
                                                          float* __restrict__ logitsc) {
  __shared__ float se[64][16];
  __shared__ int ssrc[64];
  __shared__ int sdst[64];
  __shared__ int sedge[64];
  int t = threadIdx.x;
  int base = blockIdx.x * 64;
  int c0 = t * 2;
  float wf[RR][2];
#pragma unroll
  for (int r = 0; r < RR; ++r) {
    float2 w = *(const float2*)&We[r * HC + c0];
    wf[r][0] = w.x; wf[r][1] = w.y;
  }
  float2 amv = *(const float2*)&att[c0];
  if (t < 64) {
    int i = base + t;
    sedge[t] = csr[i];
    ssrc[t] = srcc[i];
    sdst[t] = dstc[i];
  }
  __syncthreads();
  {
    int k = t >> 2, r0 = (t & 3) * 4;
    int e = sedge[k];
    float4 v;
    if (e < EE) v = *(const float4*)&eattr[(size_t)e * RR + r0];
    else        v = make_float4(0.5f, 0.5f, 0.5f, 0.5f);
    se[k][r0 + 0] = v.x; se[k][r0 + 1] = v.y;
    se[k][r0 + 2] = v.z; se[k][r0 + 3] = v.w;
  }
  __syncthreads();
  int h = t >> 5;
#pragma unroll 2
  for (int k = 0; k < 64; ++k) {
    int s = ssrc[k], d = sdst[k];
    float2 lv = *(const float2*)&xlr[(size_t)s * NC + c0];
    float2 rv = *(const float2*)&xlr[(size_t)d * NC + HC + c0];
    const float4* sk = (const float4*)se[k];
    float4 e0 = sk[0], e1 = sk[1], e2 = sk[2], e3 = sk[3];
    float er[RR] = {e0.x, e0.y, e0.z, e0.w, e1.x, e1.y, e1.z, e1.w,
                    e2.x, e2.y, e2.z, e2.w, e3.x, e3.y, e3.z, e3.w};
    float ep0 = 0.f, ep1 = 0.f;
#pragma unroll
    for (int r = 0; r < RR; ++r) { ep0 += er[r] * wf[r][0]; ep1 += er[r] * wf[r][1]; }
    float z0 = lv.x + rv.x + ep0;
    float z1 = lv.y + rv.y + ep1;
    z0 = (z0 > 0.f) ? z0 : 0.2f * z0;
    z1 = (z1 > 0.f) ? z1 : 0.2f * z1;
    float p = z0 * amv.x + z1 * amv.y;
    p += __shfl_xor(p, 1);
    p += __shfl_xor(p, 2);
    p += __shfl_xor(p, 4);
    p += __shfl_xor(p, 8);
    p += __shfl_xor(p, 16);
    if ((t & 31) == 0) logitsc[(size_t)(base + k) * 8 + h] = p;
  }
}

// ---------------- per-node segment softmax (CSR-contiguous, in-place) ----------------
__global__ __launch_bounds__(256) void softmax_kernel(const int* __restrict__ offs,
                                                      float* __restrict__ logitsc) {
  int lane = threadIdx.x & 63;
  int n = blockIdx.x * 4 + (threadIdx.x >> 6);
  int h = lane & 7, i0 = lane >> 3;
  int beg = offs[n], end = offs[n + 1];
  float m = -1e30f;
  for (int i = beg + i0; i < end; i += 8) m = fmaxf(m, logitsc[(size_t)i * 8 + h]);
  m = fmaxf(m, __shfl_xor(m, 8));
  m = fmaxf(m, __shfl_xor(m, 16));
  m = fmaxf(m, __shfl_xor(m, 32));
  float s = 0.f;
  for (int i = beg + i0; i < end; i += 8) {
    size_t idx = (size_t)i * 8 + h;
    float v = __expf(logitsc[idx] - m);
    logitsc[idx] = v;
    s += v;
  }
  s += __shfl_xor(s, 8);
  s += __shfl_xor(s, 16);
  s += __shfl_xor(s, 32);
  float inv = 1.f / (s + 1e-16f);
  for (int i = beg + i0; i < end; i += 8) {
    size_t idx = (size_t)i * 8 + h;
    logitsc[idx] *= inv;
  }
}

// ---------------- layer-1 aggregation (+bias), emits packed split-bf16 A for layer 2 ----------------
__global__ __launch_bounds__(256) void aggregate_concat_kernel(const int* __restrict__ srcc,
                                                               const int* __restrict__ offs,
                                                               const float* __restrict__ alphac,
                                                               const float* __restrict__ xlr,
                                                               const float* __restrict__ bias,
                                                               unsigned short* __restrict__ Ah2,
                                                               unsigned short* __restrict__ Al2) {
  int n = blockIdx.x, t = threadIdx.x;
  int beg = offs[n], end = offs[n + 1];
  int c0 = t, c1 = t + 256;
  int h0 = t >> 6, h1 = h0 + 4;
  float acc0 = 0.f, acc1 = 0.f;
#pragma unroll 2
  for (int i = beg; i < end; ++i) {
    int s = srcc[i];
    float a0 = alphac[(size_t)i * 8 + h0];
    float a1 = alphac[(size_t)i * 8 + h1];
    acc0 += a0 * xlr[(size_t)s * NC + c0];
    acc1 += a1 * xlr[(size_t)s * NC + c1];
  }
  float v0 = acc0 + bias[c0];
  float v1 = acc1 + bias[c1];
  int r = n & 127, rbk = n >> 7;
  // packed layout [rb][kb=16][r=128][k'=32], chunk swizzle keyed by r
#pragma unroll
  for (int u = 0; u < 2; ++u) {
    int c = u ? c1 : c0;
    float v = u ? v1 : v0;
    int kb = c >> 5, ch = (c >> 3) & 3, j = c & 7;
    int chs = (ch + (r >> 1)) & 3;
    size_t idx = ((size_t)rbk * 16 + kb) * 4096 + (size_t)r * 32 + chs * 8 + j;
    unsigned short h = f2bf(v);
    Ah2[idx] = h;
    Al2[idx] = f2bf(v - bf2f(h));
  }
}

// ---------------- layer-2 aggregation, mean over heads (+bias2) ----------------
__global__ __launch_bounds__(256) void aggregate_mean_kernel(const int* __restrict__ srcc,
                                                             const int* __restrict__ offs,
                                                             const float* __restrict__ alphac,
                                                             const float* __restrict__ xlr,
                                                             const float* __restrict__ bias2,
                                                             float* __restrict__ out) {
  __shared__ float red[HC];
  int n = blockIdx.x, t = threadIdx.x;
  int beg = offs[n], end = offs[n + 1];
  int c0 = t, c1 = t + 256;
  int h0 = t >> 6, h1 = h0 + 4;
  float acc0 = 0.f, acc1 = 0.f;
#pragma unroll 2
  for (int i = beg; i < end; ++i) {
    int s = srcc[i];
    float a0 = alphac[(size_t)i * 8 + h0];
    float a1 = alphac[(size_t)i * 8 + h1];
    acc0 += a0 * xlr[(size_t)s * NC + c0];
    acc1 += a1 * xlr[(size_t)s * NC + c1];
  }
  red[c0] = acc0;
  red[c1] = acc1;
  __syncthreads();
  if (t < CC) {
    float ssum = 0.f;
#pragma unroll
    for (int hh = 0; hh < HH; ++hh) ssum += red[hh * CC + t];
    out[(size_t)n * CC + t] = ssum * 0.125f + bias2[t];
  }
}

extern "C" void kernel_launch(void* const* d_in, const int* in_sizes, int n_in,
                              void* d_out, int out_size, void* d_ws, size_t ws_size,
                              hipStream_t stream) {
  const float* x     = (const float*)d_in[0];
  const int*   ei    = (const int*)d_in[1];
  const float* eattr = (const float*)d_in[2];
  const float* Wl1   = (const float*)d_in[3];
  const float* bl1   = (const float*)d_in[4];
  const float* Wr1   = (const float*)d_in[5];
  const float* br1   = (const float*)d_in[6];
  const float* We1   = (const float*)d_in[7];
  const float* att1  = (const float*)d_in[8];
  const float* bias1 = (const float*)d_in[9];
  const float* Wl2   = (const float*)d_in[10];
  const float* bl2   = (const float*)d_in[11];
  const float* Wr2   = (const float*)d_in[12];
  const float* br2   = (const float*)d_in[13];
  const float* We2   = (const float*)d_in[14];
  const float* att2  = (const float*)d_in[15];
  const float* bias2 = (const float*)d_in[16];
  float* out = (float*)d_out;

  char* ws = (char*)d_ws;
  size_t off = 0;
  auto alloc = [&](size_t bytes) {
    char* p = ws + off;
    off += (bytes + 255) & ~(size_t)255;
    return p;
  };
  float* bufC = (float*)alloc((size_t)NN * NC * 4);            // fused xl|xr (both layers)
  float* logits = (float*)alloc((size_t)ET * HH * 4);          // logits -> alpha (CSR order)
  unsigned short* Ah1 = (unsigned short*)alloc((size_t)NN * FF * 2);
  unsigned short* Al1 = (unsigned short*)alloc((size_t)NN * FF * 2);
  unsigned short* Ah2 = (unsigned short*)alloc((size_t)NN * HC * 2);
  unsigned short* Al2 = (unsigned short*)alloc((size_t)NN * HC * 2);
  unsigned short* Wh1 = (unsigned short*)alloc((size_t)FF * NC * 2);
  unsigned short* Wlo1 = (unsigned short*)alloc((size_t)FF * NC * 2);
  unsigned short* Wh2 = (unsigned short*)alloc((size_t)HC * NC * 2);
  unsigned short* Wlo2 = (unsigned short*)alloc((size_t)HC * NC * 2);
  int* counts = (int*)alloc((size_t)NN * 4);
  int* offs   = (int*)alloc((size_t)(NN + 1) * 4);
  int* cursor = (int*)alloc((size_t)NN * 4);
  int* csr    = (int*)alloc((size_t)ET * 4);
  int* srcc   = (int*)alloc((size_t)ET * 4);
  int* dstc   = (int*)alloc((size_t)ET * 4);
  (void)ws_size; (void)in_sizes; (void)n_in; (void)out_size;

  // CSR build (every launch; ws is re-poisoned)
  hipMemsetAsync(counts, 0, (size_t)NN * 4, stream);
  int eb = (ET + 255) / 256;
  count_kernel<<<eb, 256, 0, stream>>>(ei, counts);
  scan_kernel<<<1, 1024, 0, stream>>>(counts, offs, cursor);
  scatter_kernel<<<eb, 256, 0, stream>>>(ei, cursor, csr, srcc, dstc);

  // pack operands
  pack_a_kernel<<<(NN / 128) * (FF / 32), 256, 0, stream>>>(x, Ah1, Al1, FF);
  pack_w_kernel<<<(NC / 128) * (FF / 32), 256, 0, stream>>>(Wl1, Wr1, Wh1, Wlo1, FF);
  pack_w_kernel<<<(NC / 128) * (HC / 32), 256, 0, stream>>>(Wl2, Wr2, Wh2, Wlo2, HC);

  dim3 ggrid(NC / 128, NN / 128);
  int elb = ET / 64;

  // ---- layer 1 ----
  gemm_mfma_kernel<<<ggrid, 256, 0, stream>>>(Ah1, Al1, Wh1, Wlo1, bl1, br1, bufC, FF);
  edge_logits_kernel<<<elb, 256, 0, stream>>>(csr, srcc, dstc, eattr, We1, att1, bufC, logits);
  softmax_kernel<<<NN / 4, 256, 0, stream>>>(offs, logits);
  aggregate_concat_kernel<<<NN, 256, 0, stream>>>(srcc, offs, logits, bufC, bias1, Ah2, Al2);

  // ---- layer 2 ----
  gemm_mfma_kernel<<<ggrid, 256, 0, stream>>>(Ah2, Al2, Wh2, Wlo2, bl2, br2, bufC, HC);
  edge_logits_kernel<<<elb, 256, 0, stream>>>(csr, srcc, dstc, eattr, We2, att2, bufC, logits);
  softmax_kernel<<<NN / 4, 256, 0, stream>>>(offs, logits);
  aggregate_mean_kernel<<<NN, 256, 0, stream>>>(srcc, offs, logits, bufC, bias2, out);
}

// Round 4
// 496.482 us; speedup vs baseline: 1.7559x; 1.1133x over previous
//
#include <hip/hip_runtime.h>
#include <cstdint>

#define NN 16384
#define FF 128
#define RR 16
#define HH 8
#define CC 64
#define HC 512
#define NC 1024          // fused Wl|Wr output width
#define EE 163840
#define ET (EE + NN)     // 180224 edges including self-loops (64-divisible)

typedef __attribute__((ext_vector_type(4))) float f32x4;
typedef __attribute__((ext_vector_type(8))) short short8;

__device__ __forceinline__ unsigned short f2bf(float f) {
  unsigned u = __builtin_bit_cast(unsigned, f);
  u = (u + 0x7FFFu + ((u >> 16) & 1u)) >> 16;   // RNE
  return (unsigned short)u;
}
__device__ __forceinline__ float bf2f(unsigned short b) {
  unsigned u = ((unsigned)b) << 16;
  return __builtin_bit_cast(float, u);
}

__device__ __forceinline__ void gl_lds16(const void* g, void* l) {
  __builtin_amdgcn_global_load_lds(
      (const __attribute__((address_space(1))) unsigned int*)g,
      (__attribute__((address_space(3))) unsigned int*)l, 16, 0, 0);
}

// ---------------- CSR build (dst-sorted) ----------------
__global__ __launch_bounds__(256) void count_kernel(const int* __restrict__ ei,
                                                    int* __restrict__ counts) {
  int e = blockIdx.x * 256 + threadIdx.x;
  if (e >= ET) return;
  int d = (e < EE) ? ei[EE + e] : (e - EE);
  atomicAdd(&counts[d], 1);
}

__global__ __launch_bounds__(1024) void scan_kernel(const int* __restrict__ counts,
                                                    int* __restrict__ offs,
                                                    int* __restrict__ cursor) {
  __shared__ int part[1024];
  int t = threadIdx.x;
  int base = t * 16;
  int loc[16];
  int s = 0;
#pragma unroll
  for (int i = 0; i < 16; ++i) { loc[i] = s; s += counts[base + i]; }
  part[t] = s;
  __syncthreads();
  for (int off = 1; off < 1024; off <<= 1) {
    int v = (t >= off) ? part[t - off] : 0;
    __syncthreads();
    part[t] += v;
    __syncthreads();
  }
  int excl = part[t] - s;
#pragma unroll
  for (int i = 0; i < 16; ++i) {
    int o = excl + loc[i];
    offs[base + i] = o;
    cursor[base + i] = o;
  }
  if (t == 1023) offs[NN] = part[1023];
}

__global__ __launch_bounds__(256) void scatter_kernel(const int* __restrict__ ei,
                                                      int* __restrict__ cursor,
                                                      int* __restrict__ csr,
                                                      int* __restrict__ srcc,
                                                      int* __restrict__ dstc) {
  int e = blockIdx.x * 256 + threadIdx.x;
  if (e >= ET) return;
  int s, d;
  if (e < EE) { s = ei[e]; d = ei[EE + e]; }
  else        { s = d = e - EE; }
  int p = atomicAdd(&cursor[d], 1);
  csr[p] = e;
  srcc[p] = s;
  dstc[p] = d;
}

// ---------------- packing: fp32 -> split bf16 (hi/lo), k-chunk-tiled + swizzled ----------------
__global__ __launch_bounds__(256) void pack_a_kernel(const float* __restrict__ A,
                                                     unsigned short* __restrict__ Ah,
                                                     unsigned short* __restrict__ Al,
                                                     int K) {
  int nkb = K >> 5;
  int rb = blockIdx.x / nkb, kb = blockIdx.x % nkb;
  int t = threadIdx.x;
  size_t obase = ((size_t)rb * nkb + kb) * 4096;
#pragma unroll
  for (int u = 0; u < 2; ++u) {
    int lin = t + u * 256;          // r*4 + ch
    int r = lin >> 2, ch = lin & 3;
    int chs = (ch + (r >> 1)) & 3;
    const float* src = &A[(size_t)(rb * 128 + r) * K + kb * 32 + ch * 8];
    float4 v0 = *(const float4*)src;
    float4 v1 = *(const float4*)(src + 4);
    float v[8] = {v0.x, v0.y, v0.z, v0.w, v1.x, v1.y, v1.z, v1.w};
    short8 hv, lv;
#pragma unroll
    for (int j = 0; j < 8; ++j) {
      unsigned short h = f2bf(v[j]);
      unsigned short l = f2bf(v[j] - bf2f(h));
      hv[j] = (short)h; lv[j] = (short)l;
    }
    size_t o = obase + (size_t)r * 32 + chs * 8;
    *(short8*)&Ah[o] = hv;
    *(short8*)&Al[o] = lv;
  }
}

__global__ __launch_bounds__(256) void pack_w_kernel(const float* __restrict__ Wl,
                                                     const float* __restrict__ Wr,
                                                     unsigned short* __restrict__ Bh,
                                                     unsigned short* __restrict__ Bl,
                                                     int K) {
  int nkb = K >> 5;
  int nb = blockIdx.x / nkb, kb = blockIdx.x % nkb;
  int t = threadIdx.x;
  size_t obase = ((size_t)nb * nkb + kb) * 4096;
#pragma unroll
  for (int u = 0; u < 2; ++u) {
    int lin = t + u * 256;          // n*4 + ch
    int n = lin >> 2, ch = lin & 3;
    int chs = (ch + (n >> 1)) & 3;
    int gn = nb * 128 + n;
    const float* W = (gn < HC) ? Wl : Wr;
    int cn = gn & (HC - 1);
    short8 hv, lv;
#pragma unroll
    for (int j = 0; j < 8; ++j) {
      float f = W[(size_t)(kb * 32 + ch * 8 + j) * HC + cn];
      unsigned short h = f2bf(f);
      unsigned short l = f2bf(f - bf2f(h));
      hv[j] = (short)h; lv[j] = (short)l;
    }
    size_t o = obase + (size_t)n * 32 + chs * 8;
    *(short8*)&Bh[o] = hv;
    *(short8*)&Bl[o] = lv;
  }
}

// ---------------- split-bf16 MFMA GEMM: C[M x 1024] = A[M x K] @ [Wl|Wr] + [bl|br] ----------------
__global__ __launch_bounds__(256) void gemm_mfma_kernel(const unsigned short* __restrict__ Ah,
                                                        const unsigned short* __restrict__ Al,
                                                        const unsigned short* __restrict__ Bh,
                                                        const unsigned short* __restrict__ Bl,
                                                        const float* __restrict__ bl,
                                                        const float* __restrict__ br,
                                                        float* __restrict__ C, int K) {
  __shared__ unsigned short lAh[4096], lAl[4096], lBh[4096], lBl[4096];
  int tid = threadIdx.x;
  int wave = tid >> 6, lane = tid & 63;
  int l15 = lane & 15, quad = lane >> 4;
  int wm = wave >> 1, wn = wave & 1;
  int nb = blockIdx.x, rb = blockIdx.y;
  int nkb = K >> 5;

  const unsigned short* src = (wave == 0) ? Ah : (wave == 1) ? Al : (wave == 2) ? Bh : Bl;
  unsigned short* dst = (wave == 0) ? lAh : (wave == 1) ? lAl : (wave == 2) ? lBh : lBl;
  int blk = (wave < 2) ? rb : nb;
  size_t gstep = 4096;
  const unsigned short* gbase = src + ((size_t)blk * nkb) * gstep + lane * 8;

  f32x4 acc[4][4];
#pragma unroll
  for (int i = 0; i < 4; ++i)
#pragma unroll
    for (int j = 0; j < 4; ++j) acc[i][j] = (f32x4){0.f, 0.f, 0.f, 0.f};

  int offA[4], offB[4];
#pragma unroll
  for (int t = 0; t < 4; ++t) {
    int ra = wm * 64 + t * 16 + l15;
    offA[t] = ra * 32 + ((quad + (ra >> 1)) & 3) * 8;
    int rbn = wn * 64 + t * 16 + l15;
    offB[t] = rbn * 32 + ((quad + (rbn >> 1)) & 3) * 8;
  }

  for (int kb = 0; kb < nkb; ++kb) {
    const unsigned short* g = gbase + (size_t)kb * gstep;
#pragma unroll
    for (int i = 0; i < 8; ++i)
      gl_lds16(g + i * 512, dst + i * 512);
    __syncthreads();

    short8 ah[4], al_[4], bh[4], bl_[4];
#pragma unroll
    for (int t = 0; t < 4; ++t) {
      ah[t]  = *(const short8*)&lAh[offA[t]];
      al_[t] = *(const short8*)&lAl[offA[t]];
      bh[t]  = *(const short8*)&lBh[offB[t]];
      bl_[t] = *(const short8*)&lBl[offB[t]];
    }
#pragma unroll
    for (int tm = 0; tm < 4; ++tm)
#pragma unroll
      for (int tn = 0; tn < 4; ++tn) {
        acc[tm][tn] = __builtin_amdgcn_mfma_f32_16x16x32_bf16(ah[tm], bh[tn], acc[tm][tn], 0, 0, 0);
        acc[tm][tn] = __builtin_amdgcn_mfma_f32_16x16x32_bf16(ah[tm], bl_[tn], acc[tm][tn], 0, 0, 0);
        acc[tm][tn] = __builtin_amdgcn_mfma_f32_16x16x32_bf16(al_[tm], bh[tn], acc[tm][tn], 0, 0, 0);
      }
    __syncthreads();
  }

#pragma unroll
  for (int tm = 0; tm < 4; ++tm) {
    int row = rb * 128 + wm * 64 + tm * 16 + quad * 4;
#pragma unroll
    for (int tn = 0; tn < 4; ++tn) {
      int col = nb * 128 + wn * 64 + tn * 16 + l15;
      float bias = (col < HC) ? bl[col] : br[col - HC];
#pragma unroll
      for (int r = 0; r < 4; ++r)
        C[(size_t)(row + r) * NC + col] = acc[tm][tn][r] + bias;
    }
  }
}

// ---------------- edge logits: one block per 64 CSR slots ----------------
// __launch_bounds__(256, 4): 4 waves/EU -> 128-VGPR budget so wf[16][2] (32 regs)
// stays resident (R3 regression: default heuristic chose VGPR=32 and rematerialized).
__global__ __launch_bounds__(256, 4) void edge_logits_kernel(const int* __restrict__ csr,
                                                             const int* __restrict__ srcc,
                                                             const int* __restrict__ dstc,
                                                             const float* __restrict__ eattr,
                                                             const float* __restrict__ We,
                                                             const float* __restrict__ att,
                                                             const float* __restrict__ xlr,
                                                             float* __restrict__ logitsc) {
  __shared__ float se[64][16];
  __shared__ int ssrc[64];
  __shared__ int sdst[64];
  __shared__ int sedge[64];
  int t = threadIdx.x;
  int base = blockIdx.x * 64;
  int c0 = t * 2;
  float wf[RR][2];
#pragma unroll
  for (int r = 0; r < RR; ++r) {
    float2 w = *(const float2*)&We[r * HC + c0];
    wf[r][0] = w.x; wf[r][1] = w.y;
  }
  float2 amv = *(const float2*)&att[c0];
  if (t < 64) {
    int i = base + t;
    sedge[t] = csr[i];
    ssrc[t] = srcc[i];
    sdst[t] = dstc[i];
  }
  __syncthreads();
  {
    int k = t >> 2, r0 = (t & 3) * 4;
    int e = sedge[k];
    float4 v;
    if (e < EE) v = *(const float4*)&eattr[(size_t)e * RR + r0];
    else        v = make_float4(0.5f, 0.5f, 0.5f, 0.5f);
    se[k][r0 + 0] = v.x; se[k][r0 + 1] = v.y;
    se[k][r0 + 2] = v.z; se[k][r0 + 3] = v.w;
  }
  __syncthreads();
  int h = t >> 5;
#pragma unroll 2
  for (int k = 0; k < 64; ++k) {
    int s = ssrc[k], d = sdst[k];
    float2 lv = *(const float2*)&xlr[(size_t)s * NC + c0];
    float2 rv = *(const float2*)&xlr[(size_t)d * NC + HC + c0];
    const float4* sk = (const float4*)se[k];
    float4 e0 = sk[0], e1 = sk[1], e2 = sk[2], e3 = sk[3];
    float er[RR] = {e0.x, e0.y, e0.z, e0.w, e1.x, e1.y, e1.z, e1.w,
                    e2.x, e2.y, e2.z, e2.w, e3.x, e3.y, e3.z, e3.w};
    float ep0 = 0.f, ep1 = 0.f;
#pragma unroll
    for (int r = 0; r < RR; ++r) {
      ep0 = fmaf(er[r], wf[r][0], ep0);
      ep1 = fmaf(er[r], wf[r][1], ep1);
    }
    float z0 = lv.x + rv.x + ep0;
    float z1 = lv.y + rv.y + ep1;
    z0 = fmaf(0.2f, fminf(z0, 0.f), fmaxf(z0, 0.f));
    z1 = fmaf(0.2f, fminf(z1, 0.f), fmaxf(z1, 0.f));
    float p = fmaf(z0, amv.x, z1 * amv.y);
    p += __shfl_xor(p, 1);
    p += __shfl_xor(p, 2);
    p += __shfl_xor(p, 4);
    p += __shfl_xor(p, 8);
    p += __shfl_xor(p, 16);
    if ((t & 31) == 0) logitsc[(size_t)(base + k) * 8 + h] = p;
  }
}

// ---------------- per-node segment softmax (CSR-contiguous, in-place) ----------------
__global__ __launch_bounds__(256) void softmax_kernel(const int* __restrict__ offs,
                                                      float* __restrict__ logitsc) {
  int lane = threadIdx.x & 63;
  int n = blockIdx.x * 4 + (threadIdx.x >> 6);
  int h = lane & 7, i0 = lane >> 3;
  int beg = offs[n], end = offs[n + 1];
  float m = -1e30f;
  for (int i = beg + i0; i < end; i += 8) m = fmaxf(m, logitsc[(size_t)i * 8 + h]);
  m = fmaxf(m, __shfl_xor(m, 8));
  m = fmaxf(m, __shfl_xor(m, 16));
  m = fmaxf(m, __shfl_xor(m, 32));
  float s = 0.f;
  for (int i = beg + i0; i < end; i += 8) {
    size_t idx = (size_t)i * 8 + h;
    float v = __expf(logitsc[idx] - m);
    logitsc[idx] = v;
    s += v;
  }
  s += __shfl_xor(s, 8);
  s += __shfl_xor(s, 16);
  s += __shfl_xor(s, 32);
  float inv = 1.f / (s + 1e-16f);
  for (int i = beg + i0; i < end; i += 8) {
    size_t idx = (size_t)i * 8 + h;
    logitsc[idx] *= inv;
  }
}

// ---------------- layer-1 aggregation (+bias), emits packed split-bf16 A for layer 2 ----------------
__global__ __launch_bounds__(256) void aggregate_concat_kernel(const int* __restrict__ srcc,
                                                               const int* __restrict__ offs,
                                                               const float* __restrict__ alphac,
                                                               const float* __restrict__ xlr,
                                                               const float* __restrict__ bias,
                                                               unsigned short* __restrict__ Ah2,
                                                               unsigned short* __restrict__ Al2) {
  int n = blockIdx.x, t = threadIdx.x;
  int beg = offs[n], end = offs[n + 1];
  int c0 = t, c1 = t + 256;
  int h0 = t >> 6, h1 = h0 + 4;
  float acc0 = 0.f, acc1 = 0.f;
#pragma unroll 2
  for (int i = beg; i < end; ++i) {
    int s = srcc[i];
    float a0 = alphac[(size_t)i * 8 + h0];
    float a1 = alphac[(size_t)i * 8 + h1];
    acc0 += a0 * xlr[(size_t)s * NC + c0];
    acc1 += a1 * xlr[(size_t)s * NC + c1];
  }
  float v0 = acc0 + bias[c0];
  float v1 = acc1 + bias[c1];
  int r = n & 127, rbk = n >> 7;
#pragma unroll
  for (int u = 0; u < 2; ++u) {
    int c = u ? c1 : c0;
    float v = u ? v1 : v0;
    int kb = c >> 5, ch = (c >> 3) & 3, j = c & 7;
    int chs = (ch + (r >> 1)) & 3;
    size_t idx = ((size_t)rbk * 16 + kb) * 4096 + (size_t)r * 32 + chs * 8 + j;
    unsigned short h = f2bf(v);
    Ah2[idx] = h;
    Al2[idx] = f2bf(v - bf2f(h));
  }
}

// ---------------- layer-2 aggregation, mean over heads (+bias2) ----------------
__global__ __launch_bounds__(256) void aggregate_mean_kernel(const int* __restrict__ srcc,
                                                             const int* __restrict__ offs,
                                                             const float* __restrict__ alphac,
                                                             const float* __restrict__ xlr,
                                                             const float* __restrict__ bias2,
                                                             float* __restrict__ out) {
  __shared__ float red[HC];
  int n = blockIdx.x, t = threadIdx.x;
  int beg = offs[n], end = offs[n + 1];
  int c0 = t, c1 = t + 256;
  int h0 = t >> 6, h1 = h0 + 4;
  float acc0 = 0.f, acc1 = 0.f;
#pragma unroll 2
  for (int i = beg; i < end; ++i) {
    int s = srcc[i];
    float a0 = alphac[(size_t)i * 8 + h0];
    float a1 = alphac[(size_t)i * 8 + h1];
    acc0 += a0 * xlr[(size_t)s * NC + c0];
    acc1 += a1 * xlr[(size_t)s * NC + c1];
  }
  red[c0] = acc0;
  red[c1] = acc1;
  __syncthreads();
  if (t < CC) {
    float ssum = 0.f;
#pragma unroll
    for (int hh = 0; hh < HH; ++hh) ssum += red[hh * CC + t];
    out[(size_t)n * CC + t] = ssum * 0.125f + bias2[t];
  }
}

extern "C" void kernel_launch(void* const* d_in, const int* in_sizes, int n_in,
                              void* d_out, int out_size, void* d_ws, size_t ws_size,
                              hipStream_t stream) {
  const float* x     = (const float*)d_in[0];
  const int*   ei    = (const int*)d_in[1];
  const float* eattr = (const float*)d_in[2];
  const float* Wl1   = (const float*)d_in[3];
  const float* bl1   = (const float*)d_in[4];
  const float* Wr1   = (const float*)d_in[5];
  const float* br1   = (const float*)d_in[6];
  const float* We1   = (const float*)d_in[7];
  const float* att1  = (const float*)d_in[8];
  const float* bias1 = (const float*)d_in[9];
  const float* Wl2   = (const float*)d_in[10];
  const float* bl2   = (const float*)d_in[11];
  const float* Wr2   = (const float*)d_in[12];
  const float* br2   = (const float*)d_in[13];
  const float* We2   = (const float*)d_in[14];
  const float* att2  = (const float*)d_in[15];
  const float* bias2 = (const float*)d_in[16];
  float* out = (float*)d_out;

  char* ws = (char*)d_ws;
  size_t off = 0;
  auto alloc = [&](size_t bytes) {
    char* p = ws + off;
    off += (bytes + 255) & ~(size_t)255;
    return p;
  };
  float* bufC = (float*)alloc((size_t)NN * NC * 4);            // fused xl|xr (both layers)
  float* logits = (float*)alloc((size_t)ET * HH * 4);          // logits -> alpha (CSR order)
  unsigned short* Ah1 = (unsigned short*)alloc((size_t)NN * FF * 2);
  unsigned short* Al1 = (unsigned short*)alloc((size_t)NN * FF * 2);
  unsigned short* Ah2 = (unsigned short*)alloc((size_t)NN * HC * 2);
  unsigned short* Al2 = (unsigned short*)alloc((size_t)NN * HC * 2);
  unsigned short* Wh1 = (unsigned short*)alloc((size_t)FF * NC * 2);
  unsigned short* Wlo1 = (unsigned short*)alloc((size_t)FF * NC * 2);
  unsigned short* Wh2 = (unsigned short*)alloc((size_t)HC * NC * 2);
  unsigned short* Wlo2 = (unsigned short*)alloc((size_t)HC * NC * 2);
  int* counts = (int*)alloc((size_t)NN * 4);
  int* offs   = (int*)alloc((size_t)(NN + 1) * 4);
  int* cursor = (int*)alloc((size_t)NN * 4);
  int* csr    = (int*)alloc((size_t)ET * 4);
  int* srcc   = (int*)alloc((size_t)ET * 4);
  int* dstc   = (int*)alloc((size_t)ET * 4);
  (void)ws_size; (void)in_sizes; (void)n_in; (void)out_size;

  // CSR build (every launch; ws is re-poisoned)
  hipMemsetAsync(counts, 0, (size_t)NN * 4, stream);
  int eb = (ET + 255) / 256;
  count_kernel<<<eb, 256, 0, stream>>>(ei, counts);
  scan_kernel<<<1, 1024, 0, stream>>>(counts, offs, cursor);
  scatter_kernel<<<eb, 256, 0, stream>>>(ei, cursor, csr, srcc, dstc);

  // pack operands
  pack_a_kernel<<<(NN / 128) * (FF / 32), 256, 0, stream>>>(x, Ah1, Al1, FF);
  pack_w_kernel<<<(NC / 128) * (FF / 32), 256, 0, stream>>>(Wl1, Wr1, Wh1, Wlo1, FF);
  pack_w_kernel<<<(NC / 128) * (HC / 32), 256, 0, stream>>>(Wl2, Wr2, Wh2, Wlo2, HC);

  dim3 ggrid(NC / 128, NN / 128);
  int elb = ET / 64;

  // ---- layer 1 ----
  gemm_mfma_kernel<<<ggrid, 256, 0, stream>>>(Ah1, Al1, Wh1, Wlo1, bl1, br1, bufC, FF);
  edge_logits_kernel<<<elb, 256, 0, stream>>>(csr, srcc, dstc, eattr, We1, att1, bufC, logits);
  softmax_kernel<<<NN / 4, 256, 0, stream>>>(offs, logits);
  aggregate_concat_kernel<<<NN, 256, 0, stream>>>(srcc, offs, logits, bufC, bias1, Ah2, Al2);

  // ---- layer 2 ----
  gemm_mfma_kernel<<<ggrid, 256, 0, stream>>>(Ah2, Al2, Wh2, Wlo2, bl2, br2, bufC, HC);
  edge_logits_kernel<<<elb, 256, 0, stream>>>(csr, srcc, dstc, eattr, We2, att2, bufC, logits);
  softmax_kernel<<<NN / 4, 256, 0, stream>>>(offs, logits);
  aggregate_mean_kernel<<<NN, 256, 0, stream>>>(srcc, offs, logits, bufC, bias2, out);
}